// Round 7
// baseline (238.447 us; speedup 1.0000x reference)
//
#include <hip/hip_runtime.h>
#include <math.h>

#define BB 512
#define LL 128
#define DD 256
#define NREST 127            // L-1
#define EPSN 1e-12f

#define TI 128               // i-tile and k-tile per block
#define NBLK (4 * 512)       // score grid size

typedef float f32x4 __attribute__((ext_vector_type(4)));
typedef long  long2v __attribute__((ext_vector_type(2)));

// async global->LDS, 16B per lane; LDS base wave-uniform (HW adds lane*16)
#define GLD16(gp, lp) __builtin_amdgcn_global_load_lds( \
    (const __attribute__((address_space(1))) void*)(gp), \
    (__attribute__((address_space(3))) void*)(lp), 16, 0, 0)

// ---- Kernel 1: norm + normalize + cvt fp8(e4m3), column-permuted, split Af/Rf ----
// Row layout (256 B): within each 64-byte block, 8-byte groups stored in order
// 0,4,1,5,2,6,3,7 (orig group g -> pos g<4 ? 2g : 2(g-4)+1). A 16-byte LDS
// fragment read at offset quad*16 then yields [ks0 frag | ks1 frag] for that quad.
// Rf[b][r] holds row l=r+1; Rf[b][127] zeroed so score needs no masking while staging.
// Block 0 zeroes tot/pos and the completion counter (stream-ordered before score).
__global__ __launch_bounds__(256) void prep_kernel(const float* __restrict__ in,
                                                   unsigned char* __restrict__ Af,
                                                   unsigned char* __restrict__ Rf,
                                                   float* __restrict__ totpos) {
    if (blockIdx.x == 0) {
        ((f32x4*)totpos)[threadIdx.x] = (f32x4){0.f, 0.f, 0.f, 0.f};  // 1024 floats
        if (threadIdx.x == 0) ((unsigned int*)totpos)[2 * BB] = 0u;    // counter
    }
    int wid  = threadIdx.x >> 6;
    int lane = threadIdx.x & 63;
    int row  = blockIdx.x * 4 + wid;            // 0..65535
    int b    = row >> 7;
    int l    = row & 127;
    const float4 v = ((const float4*)(in + (size_t)row * DD))[lane];
    float ss = v.x*v.x + v.y*v.y + v.z*v.z + v.w*v.w;
    #pragma unroll
    for (int off = 32; off; off >>= 1) ss += __shfl_xor(ss, off);
    float sc = 1.0f / fmaxf(sqrtf(ss), EPSN);

    int p = __builtin_amdgcn_cvt_pk_fp8_f32(v.x * sc, v.y * sc, 0, false);
    p     = __builtin_amdgcn_cvt_pk_fp8_f32(v.z * sc, v.w * sc, p, true);

    // permuted byte offset for this lane's 4 elements (orig elems 4*lane..4*lane+3)
    int g_all = lane >> 1;                 // 8-elem group 0..31
    int blk   = g_all >> 3;                // 64-elem block 0..3
    int g     = g_all & 7;
    int ng    = (g < 4) ? (2 * g) : (2 * (g - 4) + 1);
    int off   = blk * 64 + ng * 8 + (lane & 1) * 4;

    if (l == 0) {
        *(unsigned int*)(Af + (size_t)b * DD + off) = (unsigned int)p;
        *(unsigned int*)(Rf + ((size_t)b * LL + 127) * DD + off) = 0u;  // pad row
    } else {
        *(unsigned int*)(Rf + ((size_t)b * LL + (l - 1)) * DD + off) = (unsigned int)p;
    }
}

// ------- Kernel 2: fp8 MFMA scores + exp + k-sum + atomic row-reduce + fused final -------
// Block: 128 anchors x 128 rest rows (127 valid) of batch j, FULL K = 256 staged
// upfront (64 KB LDS), ONE barrier, 128 MFMA/wave, exp + per-i sums, device
// atomicAdd into tot[i]/pos[i]; the LAST block to finish computes the loss.
__global__ __launch_bounds__(256) void score_kernel(const unsigned char* __restrict__ Af,
                                                    const unsigned char* __restrict__ Rf,
                                                    const int* __restrict__ label,
                                                    float* __restrict__ tot,
                                                    float* __restrict__ pos,
                                                    unsigned int* __restrict__ cnt,
                                                    float* __restrict__ out) {
    __shared__ unsigned char sA[4 * TI * 64];   // 32 KB: plane p at p*8192
    __shared__ unsigned char sR[4 * TI * 64];   // 32 KB
    __shared__ float         sP[TI * 2];
    __shared__ int           sLast;

    const int tid  = threadIdx.x;
    const int i0   = blockIdx.x * TI;
    const int j    = blockIdx.y;

    const int lane = tid & 63;
    const int w    = tid >> 6;
    const int wm   = w & 1;            // wave row (i)
    const int wn   = w >> 1;           // wave col (k_rest)
    const int rowf = lane & 15;
    const int quad = lane >> 4;
    const int lrow = lane >> 2;        // staging: row within 16-row group
    const int gct  = lane & 3;         // staging: 16B granule within 64B row

    f32x4 acc[4][4];
    #pragma unroll
    for (int a = 0; a < 4; ++a)
        #pragma unroll
        for (int b = 0; b < 4; ++b) acc[a][b] = (f32x4){0.f, 0.f, 0.f, 0.f};

    const unsigned char* aBase = Af + (size_t)i0 * DD;
    const unsigned char* rBase = Rf + (size_t)j * LL * DD;

    // ---- stage ALL of K: 64 x 1KB async loads, then one barrier ----
    #pragma unroll
    for (int p = 0; p < 4; ++p) {
        #pragma unroll
        for (int t = 0; t < 2; ++t) {
            int grp = w * 2 + t;               // 0..7, 16 rows each
            int r   = grp * 16 + lrow;
            GLD16(aBase + (size_t)r * DD + p * 64 + gct * 16, &sA[p * 8192 + grp * 1024]);
            GLD16(rBase + (size_t)r * DD + p * 64 + gct * 16, &sR[p * 8192 + grp * 1024]);
        }
    }
    __syncthreads();

    // ---- MFMA over all 4 planes (K=64 each), no barriers inside ----
    #pragma unroll
    for (int p = 0; p < 4; ++p) {
        long a0[4], a1[4], b0[4], b1[4];
        #pragma unroll
        for (int mt = 0; mt < 4; ++mt) {
            long2v lv = *(const long2v*)(&sA[p * 8192 + (wm * 64 + mt * 16 + rowf) * 64 + quad * 16]);
            a0[mt] = lv.x; a1[mt] = lv.y;
        }
        #pragma unroll
        for (int nt = 0; nt < 4; ++nt) {
            long2v lv = *(const long2v*)(&sR[p * 8192 + (wn * 64 + nt * 16 + rowf) * 64 + quad * 16]);
            b0[nt] = lv.x; b1[nt] = lv.y;
        }
        #pragma unroll
        for (int mt = 0; mt < 4; ++mt)
            #pragma unroll
            for (int nt = 0; nt < 4; ++nt)
                acc[mt][nt] = __builtin_amdgcn_mfma_f32_16x16x32_fp8_fp8(a0[mt], b0[nt], acc[mt][nt], 0, 0, 0);
        #pragma unroll
        for (int mt = 0; mt < 4; ++mt)
            #pragma unroll
            for (int nt = 0; nt < 4; ++nt)
                acc[mt][nt] = __builtin_amdgcn_mfma_f32_16x16x32_fp8_fp8(a1[mt], b1[nt], acc[mt][nt], 0, 0, 0);
    }

    // ---- epilogue: exp + sum over this wave's 64 k values ----
    // C/D layout: col(n) = lane&15, row(m) = quad*4 + reg (verified R2-R6)
    #pragma unroll
    for (int mt = 0; mt < 4; ++mt) {
        float s[4];
        #pragma unroll
        for (int r = 0; r < 4; ++r) s[r] = 0.f;
        #pragma unroll
        for (int nt = 0; nt < 4; ++nt) {
            int n = wn * 64 + nt * 16 + rowf;   // global k_rest index
            bool valid = (n < NREST);
            #pragma unroll
            for (int r = 0; r < 4; ++r)
                if (valid) s[r] += __expf(acc[mt][nt][r]);
        }
        #pragma unroll
        for (int r = 0; r < 4; ++r) {
            #pragma unroll
            for (int off = 1; off < 16; off <<= 1) s[r] += __shfl_xor(s[r], off);
        }
        if (rowf == 0) {
            #pragma unroll
            for (int r = 0; r < 4; ++r)
                sP[(wm * 64 + mt * 16 + quad * 4 + r) * 2 + wn] = s[r];
        }
    }
    __syncthreads();
    if (tid < TI) {
        int i = i0 + tid;
        float e = sP[tid * 2] + sP[tid * 2 + 1];
        atomicAdd(&tot[i], e);
        if (label[j] == label[i]) atomicAdd(&pos[i], e);
    }

    // ---- fused final: last block to finish computes the loss ----
    __threadfence();            // release our tot/pos adds
    __syncthreads();            // barrier drains vmcnt: all this block's atomics done
    if (tid == 0) sLast = (atomicAdd(cnt, 1u) == (unsigned)(NBLK - 1));
    __syncthreads();
    if (sLast) {
        // read via returning atomics -> coherence-point reads (cross-XCD safe)
        int t0 = tid, t1 = tid + 256;
        float tt0 = atomicAdd(&tot[t0], 0.0f);
        float pp0 = atomicAdd(&pos[t0], 0.0f);
        float tt1 = atomicAdd(&tot[t1], 0.0f);
        float pp1 = atomicAdd(&pos[t1], 0.0f);
        float s = (logf(tt0) - logf(pp0)) + (logf(tt1) - logf(pp1));
        #pragma unroll
        for (int off = 32; off; off >>= 1) s += __shfl_xor(s, off);
        if (lane == 0) sP[w] = s;
        __syncthreads();
        if (tid == 0) out[0] = (sP[0] + sP[1] + sP[2] + sP[3]) * (1.0f / BB);
    }
}

extern "C" void kernel_launch(void* const* d_in, const int* in_sizes, int n_in,
                              void* d_out, int out_size, void* d_ws, size_t ws_size,
                              hipStream_t stream) {
    const float* in    = (const float*)d_in[0];
    const int*   label = (const int*)d_in[1];
    float*       out   = (float*)d_out;

    unsigned char* Af  = (unsigned char*)d_ws;                // 512*256 B (128 KB)
    unsigned char* Rf  = Af + (size_t)BB * DD;                // 512*128*256 B (16 MB)
    float*         tot = (float*)(Rf + (size_t)BB * LL * DD); // 512 f32
    float*         pos = tot + BB;                            // 512 f32
    unsigned int*  cnt = (unsigned int*)(pos + BB);           // completion counter

    prep_kernel<<<(BB * LL) / 4, 256, 0, stream>>>(in, Af, Rf, tot);
    score_kernel<<<dim3(BB / TI, BB), 256, 0, stream>>>(Af, Rf, label, tot, pos, cnt, out);
}

// Round 8
// 121.290 us; speedup vs baseline: 1.9659x; 1.9659x over previous
//
#include <hip/hip_runtime.h>
#include <math.h>

#define BB 512
#define LL 128
#define DD 256
#define NREST 127            // L-1
#define EPSN 1e-12f

#define TI 128               // i-tile and k-tile per block

typedef float f32x4 __attribute__((ext_vector_type(4)));
typedef long  long2v __attribute__((ext_vector_type(2)));

// async global->LDS, 16B per lane; LDS base wave-uniform (HW adds lane*16)
#define GLD16(gp, lp) __builtin_amdgcn_global_load_lds( \
    (const __attribute__((address_space(1))) void*)(gp), \
    (__attribute__((address_space(3))) void*)(lp), 16, 0, 0)

// ---- Kernel 1: norm + normalize + cvt fp8(e4m3), column-permuted, split Af/Rf ----
// Row layout (256 B): within each 64-byte block, 8-byte groups stored in order
// 0,4,1,5,2,6,3,7 (orig group g -> pos g<4 ? 2g : 2(g-4)+1). A 16-byte LDS
// fragment read at offset quad*16 then yields [ks0 frag | ks1 frag] for that quad.
// Rf[b][r] holds row l=r+1; Rf[b][127] zeroed so score needs no masking while staging.
// Block 0 additionally zeroes tot/pos (stream-ordered before score's atomics).
__global__ __launch_bounds__(256) void prep_kernel(const float* __restrict__ in,
                                                   unsigned char* __restrict__ Af,
                                                   unsigned char* __restrict__ Rf,
                                                   float* __restrict__ totpos) {
    if (blockIdx.x == 0) {
        ((f32x4*)totpos)[threadIdx.x] = (f32x4){0.f, 0.f, 0.f, 0.f};  // 1024 floats
    }
    int wid  = threadIdx.x >> 6;
    int lane = threadIdx.x & 63;
    int row  = blockIdx.x * 4 + wid;            // 0..65535
    int b    = row >> 7;
    int l    = row & 127;
    const float4 v = ((const float4*)(in + (size_t)row * DD))[lane];
    float ss = v.x*v.x + v.y*v.y + v.z*v.z + v.w*v.w;
    #pragma unroll
    for (int off = 32; off; off >>= 1) ss += __shfl_xor(ss, off);
    float sc = 1.0f / fmaxf(sqrtf(ss), EPSN);

    int p = __builtin_amdgcn_cvt_pk_fp8_f32(v.x * sc, v.y * sc, 0, false);
    p     = __builtin_amdgcn_cvt_pk_fp8_f32(v.z * sc, v.w * sc, p, true);

    // permuted byte offset for this lane's 4 elements (orig elems 4*lane..4*lane+3)
    int g_all = lane >> 1;                 // 8-elem group 0..31
    int blk   = g_all >> 3;                // 64-elem block 0..3
    int g     = g_all & 7;
    int ng    = (g < 4) ? (2 * g) : (2 * (g - 4) + 1);
    int off   = blk * 64 + ng * 8 + (lane & 1) * 4;

    if (l == 0) {
        *(unsigned int*)(Af + (size_t)b * DD + off) = (unsigned int)p;
        *(unsigned int*)(Rf + ((size_t)b * LL + 127) * DD + off) = 0u;  // pad row
    } else {
        *(unsigned int*)(Rf + ((size_t)b * LL + (l - 1)) * DD + off) = (unsigned int)p;
    }
}

// ------- Kernel 2: fp8 MFMA scores + exp + k-sum + fused atomic row-reduce -------
// Block: 128 anchors x 128 rest rows (127 valid) of batch j, FULL K = 256 staged
// upfront (64 KB LDS), ONE barrier, 128 MFMA/wave, then exp + per-i sums and
// device atomicAdd into tot[i] / pos[i] (label-gated).
// NOTE (R7 lesson): do NOT fuse the final reduction here via last-block-done —
// the required per-block __threadfence() costs an L2 writeback per block on
// CDNA4 (non-coherent per-XCD L2s) and serialized the kernel (121 -> 238 us).
__global__ __launch_bounds__(256) void score_kernel(const unsigned char* __restrict__ Af,
                                                    const unsigned char* __restrict__ Rf,
                                                    const int* __restrict__ label,
                                                    float* __restrict__ tot,
                                                    float* __restrict__ pos) {
    __shared__ unsigned char sA[4 * TI * 64];   // 32 KB: plane p at p*8192
    __shared__ unsigned char sR[4 * TI * 64];   // 32 KB
    __shared__ float         sP[TI * 2];

    const int tid  = threadIdx.x;
    const int i0   = blockIdx.x * TI;
    const int j    = blockIdx.y;

    const int lane = tid & 63;
    const int w    = tid >> 6;
    const int wm   = w & 1;            // wave row (i)
    const int wn   = w >> 1;           // wave col (k_rest)
    const int rowf = lane & 15;
    const int quad = lane >> 4;
    const int lrow = lane >> 2;        // staging: row within 16-row group
    const int gct  = lane & 3;         // staging: 16B granule within 64B row

    f32x4 acc[4][4];
    #pragma unroll
    for (int a = 0; a < 4; ++a)
        #pragma unroll
        for (int b = 0; b < 4; ++b) acc[a][b] = (f32x4){0.f, 0.f, 0.f, 0.f};

    const unsigned char* aBase = Af + (size_t)i0 * DD;
    const unsigned char* rBase = Rf + (size_t)j * LL * DD;

    // ---- stage ALL of K: 64 x 1KB async loads, then one barrier ----
    #pragma unroll
    for (int p = 0; p < 4; ++p) {
        #pragma unroll
        for (int t = 0; t < 2; ++t) {
            int grp = w * 2 + t;               // 0..7, 16 rows each
            int r   = grp * 16 + lrow;
            GLD16(aBase + (size_t)r * DD + p * 64 + gct * 16, &sA[p * 8192 + grp * 1024]);
            GLD16(rBase + (size_t)r * DD + p * 64 + gct * 16, &sR[p * 8192 + grp * 1024]);
        }
    }
    __syncthreads();

    // ---- MFMA over all 4 planes (K=64 each), no barriers inside ----
    #pragma unroll
    for (int p = 0; p < 4; ++p) {
        long a0[4], a1[4], b0[4], b1[4];
        #pragma unroll
        for (int mt = 0; mt < 4; ++mt) {
            long2v lv = *(const long2v*)(&sA[p * 8192 + (wm * 64 + mt * 16 + rowf) * 64 + quad * 16]);
            a0[mt] = lv.x; a1[mt] = lv.y;
        }
        #pragma unroll
        for (int nt = 0; nt < 4; ++nt) {
            long2v lv = *(const long2v*)(&sR[p * 8192 + (wn * 64 + nt * 16 + rowf) * 64 + quad * 16]);
            b0[nt] = lv.x; b1[nt] = lv.y;
        }
        #pragma unroll
        for (int mt = 0; mt < 4; ++mt)
            #pragma unroll
            for (int nt = 0; nt < 4; ++nt)
                acc[mt][nt] = __builtin_amdgcn_mfma_f32_16x16x32_fp8_fp8(a0[mt], b0[nt], acc[mt][nt], 0, 0, 0);
        #pragma unroll
        for (int mt = 0; mt < 4; ++mt)
            #pragma unroll
            for (int nt = 0; nt < 4; ++nt)
                acc[mt][nt] = __builtin_amdgcn_mfma_f32_16x16x32_fp8_fp8(a1[mt], b1[nt], acc[mt][nt], 0, 0, 0);
    }

    // ---- epilogue: exp + sum over this wave's 64 k values ----
    // C/D layout: col(n) = lane&15, row(m) = quad*4 + reg (verified R2-R6)
    #pragma unroll
    for (int mt = 0; mt < 4; ++mt) {
        float s[4];
        #pragma unroll
        for (int r = 0; r < 4; ++r) s[r] = 0.f;
        #pragma unroll
        for (int nt = 0; nt < 4; ++nt) {
            int n = wn * 64 + nt * 16 + rowf;   // global k_rest index
            bool valid = (n < NREST);
            #pragma unroll
            for (int r = 0; r < 4; ++r)
                if (valid) s[r] += __expf(acc[mt][nt][r]);
        }
        #pragma unroll
        for (int r = 0; r < 4; ++r) {
            #pragma unroll
            for (int off = 1; off < 16; off <<= 1) s[r] += __shfl_xor(s[r], off);
        }
        if (rowf == 0) {
            #pragma unroll
            for (int r = 0; r < 4; ++r)
                sP[(wm * 64 + mt * 16 + quad * 4 + r) * 2 + wn] = s[r];
        }
    }
    __syncthreads();
    if (tid < TI) {
        int i = i0 + tid;
        float e = sP[tid * 2] + sP[tid * 2 + 1];
        atomicAdd(&tot[i], e);
        if (label[j] == label[i]) atomicAdd(&pos[i], e);
    }
}

// ---- Kernel 3: loss = mean_i( log tot[i] - log pos[i] ) ----
__global__ __launch_bounds__(256) void final_kernel(const float* __restrict__ tot,
                                                    const float* __restrict__ pos,
                                                    float* __restrict__ out) {
    int t0 = threadIdx.x, t1 = threadIdx.x + 256;
    float s = (logf(tot[t0]) - logf(pos[t0])) + (logf(tot[t1]) - logf(pos[t1]));
    #pragma unroll
    for (int off = 32; off; off >>= 1) s += __shfl_xor(s, off);
    __shared__ float sw[4];
    int wid = threadIdx.x >> 6;
    if ((threadIdx.x & 63) == 0) sw[wid] = s;
    __syncthreads();
    if (threadIdx.x == 0) out[0] = (sw[0] + sw[1] + sw[2] + sw[3]) * (1.0f / BB);
}

extern "C" void kernel_launch(void* const* d_in, const int* in_sizes, int n_in,
                              void* d_out, int out_size, void* d_ws, size_t ws_size,
                              hipStream_t stream) {
    const float* in    = (const float*)d_in[0];
    const int*   label = (const int*)d_in[1];
    float*       out   = (float*)d_out;

    unsigned char* Af  = (unsigned char*)d_ws;               // 512*256 B (128 KB)
    unsigned char* Rf  = Af + (size_t)BB * DD;               // 512*128*256 B (16 MB)
    float*         tot = (float*)(Rf + (size_t)BB * LL * DD); // 512 f32
    float*         pos = tot + BB;                            // 512 f32

    prep_kernel<<<(BB * LL) / 4, 256, 0, stream>>>(in, Af, Rf, tot);
    score_kernel<<<dim3(BB / TI, BB), 256, 0, stream>>>(Af, Rf, label, tot, pos);
    final_kernel<<<1, 256, 0, stream>>>(tot, pos, out);
}